// Round 17
// baseline (451.319 us; speedup 1.0000x reference)
//
#include <hip/hip_runtime.h>
#include <stdint.h>
#include <math.h>

#pragma clang fp contract(off)

#define NB 4
#define TOTA 261888
#define PRE 2000
#define POST 1000
#define CATN 4768
#define NBL 20
#define CANDCAP 4096
#define NBLK 4092          // NB * TOTA / 256
#define BPB 1023           // blocks per image (TOTA/256)
#define HBLK 65            // fat hist blocks per image: 48+12+3+1+1

__device__ __forceinline__ unsigned keyF(float f) {
  unsigned u = __float_as_uint(f);
  return (u & 0x80000000u) ? ~u : (u | 0x80000000u);
}

__device__ __forceinline__ int lvlA(int l)   { switch (l) { case 0: return 196608; case 1: return 49152; case 2: return 12288; case 3: return 3072; default: return 768; } }
__device__ __forceinline__ int lvlOff(int l) { switch (l) { case 0: return 0; case 1: return 196608; case 2: return 245760; case 3: return 258048; default: return 261120; } }
__device__ __forceinline__ int lvlK(int l)   { return l == 4 ? 768 : 2000; }
__device__ __forceinline__ int lvlKP(int l)  { return l == 4 ? 768 : 1000; }
__device__ __forceinline__ int lvlBlkStart(int l) { switch (l) { case 0: return 0; case 1: return 768; case 2: return 960; case 3: return 1008; default: return 1020; } }
__device__ __forceinline__ int lvlBlkCnt(int l)   { switch (l) { case 0: return 768; case 1: return 192; case 2: return 48; case 3: return 12; default: return 3; } }

struct InPtrs {
  const float *p0, *p1, *p2, *p3, *p4;
  const float *r0, *r1, *r2, *r3, *r4;
  const float *info;
};

__device__ __forceinline__ void gaToLvl(int ga, int& l, int& off) {
  if (ga < 196608)      { l = 0; off = 0; }
  else if (ga < 245760) { l = 1; off = 196608; }
  else if (ga < 258048) { l = 2; off = 245760; }
  else if (ga < 261120) { l = 3; off = 258048; }
  else                  { l = 4; off = 261120; }
}

__device__ __forceinline__ void fatMap(int s, int& l, int& seg) {
  if (s < 48)      { l = 0; seg = s; }
  else if (s < 60) { l = 1; seg = s - 48; }
  else if (s < 63) { l = 2; seg = s - 60; }
  else if (s == 63){ l = 3; seg = 0; }
  else             { l = 4; seg = 0; }
}

// ---------------- Kernel 1: decode + clip + score extract ----------------
__global__ __launch_bounds__(256) void k_decode(InPtrs P, float4* __restrict__ props,
                                                float* __restrict__ scores) {
  int gid = blockIdx.x * 256 + threadIdx.x;
  if (gid >= NB * TOTA) return;
  int b = gid / TOTA, ga = gid % TOTA;
  int Al, off, lg; float st; double S; const float *prp, *rgp;
  if (ga < 196608)      { Al = 196608; off = 0;      lg = 8; st = 4.0f;  S = 256.0;  prp = P.p0; rgp = P.r0; }
  else if (ga < 245760) { Al = 49152;  off = 196608; lg = 7; st = 8.0f;  S = 512.0;  prp = P.p1; rgp = P.r1; }
  else if (ga < 258048) { Al = 12288;  off = 245760; lg = 6; st = 16.0f; S = 1024.0; prp = P.p2; rgp = P.r2; }
  else if (ga < 261120) { Al = 3072;   off = 258048; lg = 5; st = 32.0f; S = 2048.0; prp = P.p3; rgp = P.r3; }
  else                  { Al = 768;    off = 261120; lg = 4; st = 64.0f; S = 4096.0; prp = P.p4; rgp = P.r4; }
  int i = ga - off;
  int cell = i / 3, rr = i - cell * 3;
  int col = cell & ((1 << lg) - 1), row = cell >> lg;
  float cx0 = ((float)col + 0.5f) * st;
  float cy0 = ((float)row + 0.5f) * st;
  const double SQ2 = 1.4142135623730951;
  const double SQH = 0.7071067811865476;
  double swd = (rr == 0) ? SQ2 : (rr == 1 ? 1.0 : SQH);
  double shd = (rr == 0) ? SQH : (rr == 1 ? 1.0 : SQ2);
  float wf = (float)(S * swd), hf = (float)(S * shd);
  float ax1 = cx0 - 0.5f * wf, ay1 = cy0 - 0.5f * hf;
  float ax2 = cx0 + 0.5f * wf, ay2 = cy0 + 0.5f * hf;
  size_t base = (size_t)b * Al + i;
  float sc = prp[base * 2];
  float4 d4 = ((const float4*)rgp)[base];
  float dx = d4.x, dy = d4.y, dw = d4.z, dh = d4.w;
  float wa = ax2 - ax1, ha = ay2 - ay1;
  float cxa = ax1 + 0.5f * wa, cya = ay1 + 0.5f * ha;
  float cx = dx * wa + cxa, cy = dy * ha + cya;
  float w = (float)exp((double)dw) * wa;
  float h = (float)exp((double)dh) * ha;
  float x1 = cx - 0.5f * w, y1 = cy - 0.5f * h;
  float x2 = cx + 0.5f * w, y2 = cy + 0.5f * h;
  float Hc = P.info[b * 3 + 0] - 1.0f, Wc = P.info[b * 3 + 1] - 1.0f;
  float4 o;
  o.x = fminf(fmaxf(x1, 0.0f), Wc);
  o.y = fminf(fmaxf(y1, 0.0f), Hc);
  o.z = fminf(fmaxf(x2, 0.0f), Wc);
  o.w = fminf(fmaxf(y2, 0.0f), Hc);
  props[gid] = o;
  scores[gid] = sc;
}

// ---------------- Kernel 2a: 8-bit LDS-privatized histogram (fat blocks) ----------------
__global__ __launch_bounds__(256) void k_hist8(const float* __restrict__ scores,
                                               unsigned* __restrict__ hist8) {
  __shared__ unsigned h[256];
  int blk = blockIdx.x;
  int b = blk / HBLK, s = blk % HBLK;
  int l, seg; fatMap(s, l, seg);
  int n = lvlA(l), off = lvlOff(l);
  int start = seg * 4096;
  int cnt_s = min(4096, n - start);
  int tid = threadIdx.x;
  h[tid] = 0;
  __syncthreads();
  const float* sc = scores + (size_t)b * TOTA + off + start;
  for (int q = tid; q < cnt_s; q += 256)
    atomicAdd(&h[keyF(sc[q]) >> 24], 1u);
  __syncthreads();
  unsigned v = h[tid];
  if (v) atomicAdd(&hist8[(b * 5 + l) * 256 + tid], v);
}

// ---------------- Kernel 2b: find 8-bit bin + rank ----------------
__global__ __launch_bounds__(256) void k_thr8(const unsigned* __restrict__ hist8,
                                              unsigned* __restrict__ c1r1) {
  __shared__ unsigned h[256];
  int bl = blockIdx.x, tid = threadIdx.x;
  h[tid] = hist8[bl * 256 + tid];
  __syncthreads();
  if (tid == 0) {
    unsigned K = (unsigned)lvlK(bl % 5), cum = 0; int c;
    for (c = 255; c > 0; --c) { if (cum + h[c] >= K) break; cum += h[c]; }
    c1r1[bl * 2] = (unsigned)c;
    c1r1[bl * 2 + 1] = K - cum;
  }
}

// ---------------- Kernel 2c: 6-bit sub-histogram within c1 ----------------
__global__ __launch_bounds__(256) void k_hist6(const float* __restrict__ scores,
                                               const unsigned* __restrict__ c1r1,
                                               unsigned* __restrict__ hist6) {
  __shared__ unsigned h[64];
  int blk = blockIdx.x;
  int b = blk / HBLK, s = blk % HBLK;
  int l, seg; fatMap(s, l, seg);
  int n = lvlA(l), off = lvlOff(l);
  int start = seg * 4096;
  int cnt_s = min(4096, n - start);
  int tid = threadIdx.x;
  int bl = b * 5 + l;
  unsigned c1 = c1r1[bl * 2];
  if (tid < 64) h[tid] = 0;
  __syncthreads();
  const float* sc = scores + (size_t)b * TOTA + off + start;
  for (int q = tid; q < cnt_s; q += 256) {
    unsigned key = keyF(sc[q]);
    if ((key >> 24) == c1) atomicAdd(&h[(key >> 18) & 63u], 1u);
  }
  __syncthreads();
  if (tid < 64) {
    unsigned v = h[tid];
    if (v) atomicAdd(&hist6[bl * 64 + tid], v);
  }
}

// ---------------- Kernel 2d: final 14-bit threshold prefix ----------------
__global__ __launch_bounds__(64) void k_thr6(const unsigned* __restrict__ hist6,
                                             const unsigned* __restrict__ c1r1,
                                             unsigned* __restrict__ T14) {
  __shared__ unsigned h[64];
  int bl = blockIdx.x, tid = threadIdx.x;
  h[tid] = hist6[bl * 64 + tid];
  __syncthreads();
  if (tid == 0) {
    unsigned r1 = c1r1[bl * 2 + 1], cum = 0; int c;
    for (c = 63; c > 0; --c) { if (cum + h[c] >= r1) break; cum += h[c]; }
    T14[bl] = (c1r1[bl * 2] << 6) | (unsigned)c;
  }
}

// ---------------- Kernel 2e: per-block candidate count (no atomics) ----------------
__global__ __launch_bounds__(256) void k_cnt(const float* __restrict__ scores,
                                             const unsigned* __restrict__ T14,
                                             unsigned* __restrict__ blockCnt) {
  __shared__ unsigned ws[4];
  int gid = blockIdx.x * 256 + threadIdx.x;
  int tid = threadIdx.x;
  int b = gid / TOTA, ga = gid % TOTA;
  int l, off; gaToLvl(ga, l, off);
  int bl = b * 5 + l;
  bool pred = (keyF(scores[gid]) >> 18) >= T14[bl];
  unsigned long long m = __ballot(pred);
  if ((tid & 63) == 0) ws[tid >> 6] = (unsigned)__popcll(m);
  __syncthreads();
  if (tid == 0) blockCnt[blockIdx.x] = ws[0] + ws[1] + ws[2] + ws[3];
}

// ---------------- Kernel 2f: segmented exclusive scan of block counts ----------------
__global__ __launch_bounds__(1024) void k_scanblk(const unsigned* __restrict__ blockCnt,
                                                  unsigned* __restrict__ blockBase,
                                                  unsigned* __restrict__ cnt) {
  __shared__ unsigned a[4096];
  __shared__ unsigned ch[1024];
  int tid = threadIdx.x;
  int q0 = tid * 4;
  unsigned a0 = (q0 + 0 < NBLK) ? blockCnt[q0 + 0] : 0u;
  unsigned a1 = (q0 + 1 < NBLK) ? blockCnt[q0 + 1] : 0u;
  unsigned a2 = (q0 + 2 < NBLK) ? blockCnt[q0 + 2] : 0u;
  unsigned a3 = (q0 + 3 < NBLK) ? blockCnt[q0 + 3] : 0u;
  unsigned p0 = a0, p1 = p0 + a1, p2 = p1 + a2, p3 = p2 + a3;
  ch[tid] = p3;
  __syncthreads();
  for (int d = 1; d < 1024; d <<= 1) {
    unsigned t = (tid >= d) ? ch[tid - d] : 0u;
    __syncthreads();
    ch[tid] += t;
    __syncthreads();
  }
  unsigned cbase = (tid > 0) ? ch[tid - 1] : 0u;
  a[q0 + 0] = cbase + p0;
  a[q0 + 1] = cbase + p1;
  a[q0 + 2] = cbase + p2;
  a[q0 + 3] = cbase + p3;
  __syncthreads();
  for (int k = 0; k < 4; ++k) {
    int g = q0 + k;
    if (g < NBLK) {
      int b = g / BPB, r = g % BPB;
      int l = (r < 768) ? 0 : (r < 960) ? 1 : (r < 1008) ? 2 : (r < 1020) ? 3 : 4;
      int ss = b * BPB + lvlBlkStart(l);
      unsigned Eg = (g > 0) ? a[g - 1] : 0u;
      unsigned Es = (ss > 0) ? a[ss - 1] : 0u;
      blockBase[g] = Eg - Es;
    }
  }
  if (tid < NBL) {
    int b = tid / 5, l = tid % 5;
    int ss = b * BPB + lvlBlkStart(l);
    int ee = ss + lvlBlkCnt(l);
    unsigned Ee = a[ee - 1];
    unsigned Es = (ss > 0) ? a[ss - 1] : 0u;
    cnt[tid] = Ee - Es;
  }
}

// ---------------- Kernel 2g: fill candidates at deterministic positions ----------------
__global__ __launch_bounds__(256) void k_fill(const float* __restrict__ scores,
                                              const unsigned* __restrict__ T14,
                                              const unsigned* __restrict__ blockBase,
                                              unsigned long long* __restrict__ cand) {
  __shared__ unsigned ws[4];
  int gid = blockIdx.x * 256 + threadIdx.x;
  int tid = threadIdx.x;
  int b = gid / TOTA, ga = gid % TOTA;
  int l, off; gaToLvl(ga, l, off);
  int bl = b * 5 + l;
  unsigned key = keyF(scores[gid]);
  bool pred = (key >> 18) >= T14[bl];
  unsigned long long m = __ballot(pred);
  int wv = tid >> 6, ln = tid & 63;
  if (ln == 0) ws[wv] = (unsigned)__popcll(m);
  __syncthreads();
  unsigned wo = 0;
  for (int q = 0; q < wv; ++q) wo += ws[q];
  unsigned pre = (unsigned)__popcll(m & ((1ull << ln) - 1ull));
  if (pred) {
    unsigned p = blockBase[blockIdx.x] + wo + pre;
    if (p < CANDCAP)
      cand[(size_t)bl * CANDCAP + p] =
          ((unsigned long long)key << 32) | (unsigned long long)(0xFFFFFFFFu - (unsigned)(ga - off));
  }
}

// ---------------- Kernel 2h: sort each 512-chunk of candidates (bitonic in LDS) ----------------
__global__ __launch_bounds__(256) void k_sortc(unsigned long long* __restrict__ cand,
                                               const unsigned* __restrict__ cnt) {
  __shared__ unsigned long long arr[512];
  int blk = blockIdx.x;
  int bl = blk >> 3, ch = blk & 7;
  int base = ch * 512;
  int num = (int)min(cnt[bl], (unsigned)CANDCAP);
  int tid = threadIdx.x;
  unsigned long long* cp = cand + (size_t)bl * CANDCAP + base;
  for (int q = tid; q < 512; q += 256)
    arr[q] = (base + q < num) ? cp[q] : 0ull;
  __syncthreads();
  for (int kk = 2; kk <= 512; kk <<= 1)
    for (int jj = kk >> 1; jj > 0; jj >>= 1) {
      for (int idx = tid; idx < 512; idx += 256) {
        int p2 = idx ^ jj;
        if (p2 > idx) {
          unsigned long long x = arr[idx], y = arr[p2];
          bool up = (idx & kk) == 0;
          if (up ? (x < y) : (x > y)) { arr[idx] = y; arr[p2] = x; }
        }
      }
      __syncthreads();
    }
  for (int q = tid; q < 512; q += 256) cp[q] = arr[q];  // write back pads too (determinism)
}

// ---------------- Kernel 2i: merge-rank scatter into sorted top-K ----------------
__global__ __launch_bounds__(256) void k_rank(const unsigned long long* __restrict__ cand,
                                              const float4* __restrict__ props,
                                              const float* __restrict__ scores,
                                              float4* __restrict__ sBox,
                                              float* __restrict__ sArea,
                                              float* __restrict__ sScore) {
  int gid = blockIdx.x * 256 + threadIdx.x;
  int bl = gid >> 12, p = gid & 4095;
  int b = bl / 5, l = bl % 5;
  int K = lvlK(l), off = lvlOff(l);
  const unsigned long long* cp = cand + (size_t)bl * CANDCAP;
  unsigned long long me = cp[p];
  int ch = p >> 9;
  int rank = p & 511;  // index within own sorted chunk = # larger (keys unique)
  for (int c2 = 0; c2 < 8; ++c2) {
    if (c2 == ch) continue;
    const unsigned long long* d = cp + c2 * 512;
    int lo = 0, hi = 512;
    while (lo < hi) {
      int mid = (lo + hi) >> 1;
      if (d[mid] > me) lo = mid + 1; else hi = mid;
    }
    rank += lo;
  }
  if (rank < K) {
    unsigned idx = 0xFFFFFFFFu - (unsigned)(me & 0xFFFFFFFFull);
    float4 bx = props[(size_t)b * TOTA + off + idx];
    float area = fmaxf(bx.z - bx.x, 0.0f) * fmaxf(bx.w - bx.y, 0.0f);
    sBox[bl * PRE + rank] = bx;
    sArea[bl * PRE + rank] = area;
    sScore[bl * PRE + rank] = scores[(size_t)b * TOTA + off + idx];
  }
}

// ---------------- Kernel 3: FUSED NMS — on-demand IoU, no mask matrix ----------------
// One block per (b,l). All boxes in LDS. Per 64-tile t:
//   (a) owning wave publishes its per-thread removed flags (__ballot) -> LDS
//   (b) wave 0: ff1 serial chain on diag words -> keep word
//   (c) all 1024 threads (2 register-resident j-boxes each) loop over the
//       tile's kept boxes (wave-uniform ffs; box_i via LDS broadcast) and
//       accumulate removed |= (j>i && IoU>0.7). Exact greedy, bit-exact.
// Diag words precomputed by all 16 waves (wave-uniform inner reads).
__global__ __launch_bounds__(1024) void k_nms(const float4* __restrict__ sBoxG,
                                              const float* __restrict__ sAreaG,
                                              const float* __restrict__ sScore,
                                              float* __restrict__ catScore,
                                              float4* __restrict__ catBox) {
  __shared__ float4 bx[PRE];
  __shared__ float  ar[PRE];
  __shared__ unsigned long long diag[PRE];
  __shared__ unsigned long long keepw[32];
  __shared__ int list[1000];
  __shared__ int sTotal;
  int bl = blockIdx.x, b = bl / 5, l = bl % 5;
  int K = lvlK(l), KP = lvlKP(l), co = l * 1000;
  int tid = threadIdx.x;
  int wave = tid >> 6, ln = tid & 63;
  int nw = (K + 63) >> 6;
  for (int r = tid; r < K; r += 1024) { bx[r] = sBoxG[bl * PRE + r]; ar[r] = sAreaG[bl * PRE + r]; }
  if (tid < 32) keepw[tid] = 0ull;
  __syncthreads();
  // diag words: pass p, wave w -> tile p*16+w; lane ln -> row base+ln
  for (int p = 0; p < 2; ++p) {
    int tt = p * 16 + wave;
    if (tt < nw) {
      int base = tt * 64;
      int r = base + ln;
      bool iv = r < K;
      float4 bi4 = make_float4(0.0f, 0.0f, 0.0f, 0.0f);
      float ai = 0.0f;
      if (iv) { bi4 = bx[r]; ai = ar[r]; }
      int lim = min(64, K - base);
      unsigned long long wacc = 0ull;
      for (int t = 0; t < lim; ++t) {
        float4 b4 = bx[base + t];   // wave-uniform -> broadcast
        float aj = ar[base + t];
        bool pred = false;
        if (iv && t > ln) {
          float ltx = fmaxf(bi4.x, b4.x), lty = fmaxf(bi4.y, b4.y);
          float rbx = fminf(bi4.z, b4.z), rby = fminf(bi4.w, b4.w);
          float wx = fmaxf(rbx - ltx, 0.0f), wy = fmaxf(rby - lty, 0.0f);
          float inter = wx * wy;
          float den = fmaxf(ai + aj - inter, 1e-9f);
          pred = (inter / den) > 0.7f;
        }
        wacc |= ((unsigned long long)(pred ? 1u : 0u)) << t;
      }
      if (iv) diag[r] = wacc;
    }
  }
  // per-thread owned j-boxes (registers)
  int j1 = tid, j2 = 1024 + tid;
  bool v1 = j1 < K, v2 = j2 < K;
  float4 bj1 = make_float4(0.0f, 0.0f, 0.0f, 0.0f), bj2 = bj1;
  float aj1 = 0.0f, aj2 = 0.0f;
  if (v1) { bj1 = bx[j1]; aj1 = ar[j1]; }
  if (v2) { bj2 = bx[j2]; aj2 = ar[j2]; }
  bool rm1 = false, rm2 = false;
  __syncthreads();  // diag ready
  for (int t = 0; t < nw; ++t) {
    // (a) publish removed word for tile t (owning wave)
    if (t < 16) {
      if (wave == t) {
        unsigned long long m = __ballot(rm1);
        if (ln == 0) keepw[t] = m;
      }
    } else {
      if (wave == t - 16) {
        unsigned long long m = __ballot(rm2);
        if (ln == 0) keepw[t] = m;
      }
    }
    __syncthreads();
    // (b) wave-0 ff1 chain -> keep word
    if (tid < 64) {
      int dr = t * 64 + tid;
      unsigned long long d = (dr < K) ? diag[dr] : 0ull;
      unsigned long long local = keepw[t];
      int lim = min(64, K - t * 64);
      unsigned long long vm = (lim >= 64) ? ~0ull : ((1ull << lim) - 1ull);
      unsigned long long todo = (~local) & vm;
      while (todo) {
        int i2 = __ffsll((long long)todo) - 1;
        unsigned lo2 = __builtin_amdgcn_readlane((unsigned)d, i2);
        unsigned hi2 = __builtin_amdgcn_readlane((unsigned)(d >> 32), i2);
        unsigned long long dd = ((unsigned long long)hi2 << 32) | (unsigned long long)lo2;
        local |= dd;
        todo &= ~dd;
        todo &= ~(1ull << i2);
      }
      if (tid == 0) keepw[t] = (~local) & vm;  // store KEEP word
    }
    __syncthreads();
    // (c) apply tile t's kept boxes to this thread's j-boxes
    unsigned long long kw = keepw[t];
    while (kw) {
      int i2 = __ffsll((long long)kw) - 1;
      kw &= kw - 1;
      int i = t * 64 + i2;
      float4 b4 = bx[i];   // uniform -> broadcast
      float ai = ar[i];
      if (v1 && j1 > i && !rm1) {
        float ltx = fmaxf(b4.x, bj1.x), lty = fmaxf(b4.y, bj1.y);
        float rbx = fminf(b4.z, bj1.z), rby = fminf(b4.w, bj1.w);
        float wx = fmaxf(rbx - ltx, 0.0f), wy = fmaxf(rby - lty, 0.0f);
        float inter = wx * wy;
        float den = fmaxf(ai + aj1 - inter, 1e-9f);
        rm1 = (inter / den) > 0.7f;
      }
      if (v2 && j2 > i && !rm2) {
        float ltx = fmaxf(b4.x, bj2.x), lty = fmaxf(b4.y, bj2.y);
        float rbx = fminf(b4.z, bj2.z), rby = fminf(b4.w, bj2.w);
        float wx = fmaxf(rbx - ltx, 0.0f), wy = fmaxf(rby - lty, 0.0f);
        float inter = wx * wy;
        float den = fmaxf(ai + aj2 - inter, 1e-9f);
        rm2 = (inter / den) > 0.7f;
      }
    }
  }
  __syncthreads();
  // stable pack: kept (index order) then suppressed (index order) — wave 0
  if (tid < 64) {
    int lane = tid;
    bool lv = lane < 32;
    unsigned long long kwv = lv ? keepw[lane] : 0ull;
    unsigned long long valid = 0ull;
    if (lv) {
      int rem = K - lane * 64;
      valid = (rem >= 64) ? ~0ull : (rem <= 0 ? 0ull : ((1ull << rem) - 1ull));
    }
    unsigned long long keep2 = kwv;
    unsigned long long supp2 = (~kwv) & valid;
    unsigned long long lmask = (1ull << lane) - 1ull;
    int base = 0;
    for (int w2 = 0; w2 < 32 && base < KP; ++w2) {
      unsigned long long word = __shfl(keep2, w2);
      int pre = __popcll(word & lmask);
      if (((word >> lane) & 1ull) && (base + pre) < KP) list[base + pre] = w2 * 64 + lane;
      base += __popcll(word);
    }
    int totalKept = base;
    if (totalKept < KP) {
      int b2 = totalKept;
      for (int w2 = 0; w2 < 32 && b2 < KP; ++w2) {
        unsigned long long word = __shfl(supp2, w2);
        int pre = __popcll(word & lmask);
        if (((word >> lane) & 1ull) && (b2 + pre) < KP) list[b2 + pre] = w2 * 64 + lane;
        b2 += __popcll(word);
      }
    }
    if (lane == 0) sTotal = totalKept;
  }
  __syncthreads();
  int totalKept = sTotal;
  for (int t = tid; t < KP; t += 1024) {
    int j = list[t];
    float s = (t < totalKept) ? sScore[bl * PRE + j] : -1.0f;
    catScore[b * CATN + co + t] = s;
    catBox[b * CATN + co + t] = bx[j];
  }
}

// ---------------- Kernel 5: final top-1000 via 5-way merge rank ----------------
__global__ __launch_bounds__(256) void k_final(const float* __restrict__ catScore,
                                               const float4* __restrict__ catBox,
                                               float* __restrict__ out) {
  int gid = blockIdx.x * 256 + threadIdx.x;
  if (gid >= NB * CATN) return;
  int b = gid / CATN, p = gid % CATN;
  int c = p / 1000; if (c > 4) c = 4;
  const float* cs = catScore + (size_t)b * CATN;
  float s = cs[p];
  unsigned long long me = ((unsigned long long)keyF(s) << 32) |
                          (unsigned long long)(0xFFFFFFFFu - (unsigned)p);
  int rank = p - c * 1000;
  for (int c2 = 0; c2 < 5; ++c2) {
    if (c2 == c) continue;
    int base = c2 * 1000, len = (c2 == 4) ? 768 : 1000;
    int lo = 0, hi = len;
    while (lo < hi) {
      int mid = (lo + hi) >> 1;
      int q = base + mid;
      unsigned long long k2 = ((unsigned long long)keyF(cs[q]) << 32) |
                              (unsigned long long)(0xFFFFFFFFu - (unsigned)q);
      if (k2 > me) lo = mid + 1; else hi = mid;
    }
    rank += lo;
  }
  if (rank < POST) {
    float4 bx = make_float4(0.0f, 0.0f, 0.0f, 0.0f);
    if (s >= 0.0f) bx = catBox[(size_t)b * CATN + p];
    float* o = out + ((size_t)b * POST + rank) * 5;
    o[0] = (float)b; o[1] = bx.x; o[2] = bx.y; o[3] = bx.z; o[4] = bx.w;
  }
}

extern "C" void kernel_launch(void* const* d_in, const int* in_sizes, int n_in,
                              void* d_out, int out_size, void* d_ws, size_t ws_size,
                              hipStream_t stream) {
  const int prSz[5] = {1572864, 393216, 98304, 24576, 6144};
  const int rgSz[5] = {3145728, 786432, 196608, 49152, 12288};
  const float* pr[5] = {nullptr, nullptr, nullptr, nullptr, nullptr};
  const float* rg[5] = {nullptr, nullptr, nullptr, nullptr, nullptr};
  const float* info = nullptr;
  for (int i = 0; i < n_in; ++i) {
    int s = in_sizes[i];
    bool m = false;
    for (int l = 0; l < 5; ++l) {
      if (s == prSz[l]) { pr[l] = (const float*)d_in[i]; m = true; break; }
      if (s == rgSz[l]) { rg[l] = (const float*)d_in[i]; m = true; break; }
    }
    if (!m && s == 12) info = (const float*)d_in[i];
  }
  InPtrs P;
  P.p0 = pr[0]; P.p1 = pr[1]; P.p2 = pr[2]; P.p3 = pr[3]; P.p4 = pr[4];
  P.r0 = rg[0]; P.r1 = rg[1]; P.r2 = rg[2]; P.r3 = rg[3]; P.r4 = rg[4];
  P.info = info;

  char* w = (char*)d_ws;
  float4* props = (float4*)w;                         w += (size_t)NB * TOTA * 16;
  float4* sBox = (float4*)w;                          w += (size_t)NBL * PRE * 16;
  float4* catBox = (float4*)w;                        w += (size_t)NB * CATN * 16;
  unsigned long long* cand = (unsigned long long*)w;  w += (size_t)NBL * CANDCAP * 8;
  float* scores = (float*)w;                          w += (size_t)NB * TOTA * 4;
  float* sArea = (float*)w;                           w += (size_t)NBL * PRE * 4;
  float* sScore = (float*)w;                          w += (size_t)NBL * PRE * 4;
  float* catScore = (float*)w;                        w += (size_t)NB * CATN * 4;
  unsigned* hist8 = (unsigned*)w;                     w += (size_t)NBL * 256 * 4;
  unsigned* hist6 = (unsigned*)w;                     w += (size_t)NBL * 64 * 4;
  unsigned* c1r1 = (unsigned*)w;                      w += (size_t)NBL * 2 * 4;
  unsigned* T14 = (unsigned*)w;                       w += (size_t)NBL * 4;
  unsigned* blockCnt = (unsigned*)w;                  w += (size_t)NBLK * 4;
  unsigned* blockBase = (unsigned*)w;                 w += (size_t)NBLK * 4;
  unsigned* cnt = (unsigned*)w;                       w += (size_t)NBL * 4;
  (void)ws_size; (void)out_size;

  hipMemsetAsync(hist8, 0, (size_t)NBL * (256 + 64) * 4, stream);

  k_decode<<<(NB * TOTA + 255) / 256, 256, 0, stream>>>(P, props, scores);
  k_hist8<<<NB * HBLK, 256, 0, stream>>>(scores, hist8);
  k_thr8<<<NBL, 256, 0, stream>>>(hist8, c1r1);
  k_hist6<<<NB * HBLK, 256, 0, stream>>>(scores, c1r1, hist6);
  k_thr6<<<NBL, 64, 0, stream>>>(hist6, c1r1, T14);
  k_cnt<<<NBLK, 256, 0, stream>>>(scores, T14, blockCnt);
  k_scanblk<<<1, 1024, 0, stream>>>(blockCnt, blockBase, cnt);
  k_fill<<<NBLK, 256, 0, stream>>>(scores, T14, blockBase, cand);
  k_sortc<<<NBL * 8, 256, 0, stream>>>(cand, cnt);
  k_rank<<<NBL * CANDCAP / 256, 256, 0, stream>>>(cand, props, scores, sBox, sArea, sScore);
  k_nms<<<NBL, 1024, 0, stream>>>(sBox, sArea, sScore, catScore, catBox);
  k_final<<<(NB * CATN + 255) / 256, 256, 0, stream>>>(catScore, catBox, (float*)d_out);
}

// Round 18
// 203.224 us; speedup vs baseline: 2.2208x; 2.2208x over previous
//
#include <hip/hip_runtime.h>
#include <stdint.h>
#include <math.h>

#pragma clang fp contract(off)

#define NB 4
#define TOTA 261888
#define PRE 2000
#define POST 1000
#define CATN 4768
#define NBL 20
#define CANDCAP 4096
#define NBLK 4092          // NB * TOTA / 256
#define BPB 1023           // blocks per image (TOTA/256)
#define HBLK 65            // fat hist blocks per image: 48+12+3+1+1

__device__ __forceinline__ unsigned keyF(float f) {
  unsigned u = __float_as_uint(f);
  return (u & 0x80000000u) ? ~u : (u | 0x80000000u);
}

__device__ __forceinline__ int lvlA(int l)   { switch (l) { case 0: return 196608; case 1: return 49152; case 2: return 12288; case 3: return 3072; default: return 768; } }
__device__ __forceinline__ int lvlOff(int l) { switch (l) { case 0: return 0; case 1: return 196608; case 2: return 245760; case 3: return 258048; default: return 261120; } }
__device__ __forceinline__ int lvlK(int l)   { return l == 4 ? 768 : 2000; }
__device__ __forceinline__ int lvlKP(int l)  { return l == 4 ? 768 : 1000; }
__device__ __forceinline__ int lvlBlkStart(int l) { switch (l) { case 0: return 0; case 1: return 768; case 2: return 960; case 3: return 1008; default: return 1020; } }
__device__ __forceinline__ int lvlBlkCnt(int l)   { switch (l) { case 0: return 768; case 1: return 192; case 2: return 48; case 3: return 12; default: return 3; } }

struct InPtrs {
  const float *p0, *p1, *p2, *p3, *p4;
  const float *r0, *r1, *r2, *r3, *r4;
  const float *info;
};

__device__ __forceinline__ void gaToLvl(int ga, int& l, int& off) {
  if (ga < 196608)      { l = 0; off = 0; }
  else if (ga < 245760) { l = 1; off = 196608; }
  else if (ga < 258048) { l = 2; off = 245760; }
  else if (ga < 261120) { l = 3; off = 258048; }
  else                  { l = 4; off = 261120; }
}

__device__ __forceinline__ void fatMap(int s, int& l, int& seg) {
  if (s < 48)      { l = 0; seg = s; }
  else if (s < 60) { l = 1; seg = s - 48; }
  else if (s < 63) { l = 2; seg = s - 60; }
  else if (s == 63){ l = 3; seg = 0; }
  else             { l = 4; seg = 0; }
}

// ---------------- Kernel 1: decode + clip + score extract ----------------
__global__ __launch_bounds__(256) void k_decode(InPtrs P, float4* __restrict__ props,
                                                float* __restrict__ scores) {
  int gid = blockIdx.x * 256 + threadIdx.x;
  if (gid >= NB * TOTA) return;
  int b = gid / TOTA, ga = gid % TOTA;
  int Al, off, lg; float st; double S; const float *prp, *rgp;
  if (ga < 196608)      { Al = 196608; off = 0;      lg = 8; st = 4.0f;  S = 256.0;  prp = P.p0; rgp = P.r0; }
  else if (ga < 245760) { Al = 49152;  off = 196608; lg = 7; st = 8.0f;  S = 512.0;  prp = P.p1; rgp = P.r1; }
  else if (ga < 258048) { Al = 12288;  off = 245760; lg = 6; st = 16.0f; S = 1024.0; prp = P.p2; rgp = P.r2; }
  else if (ga < 261120) { Al = 3072;   off = 258048; lg = 5; st = 32.0f; S = 2048.0; prp = P.p3; rgp = P.r3; }
  else                  { Al = 768;    off = 261120; lg = 4; st = 64.0f; S = 4096.0; prp = P.p4; rgp = P.r4; }
  int i = ga - off;
  int cell = i / 3, rr = i - cell * 3;
  int col = cell & ((1 << lg) - 1), row = cell >> lg;
  float cx0 = ((float)col + 0.5f) * st;
  float cy0 = ((float)row + 0.5f) * st;
  const double SQ2 = 1.4142135623730951;
  const double SQH = 0.7071067811865476;
  double swd = (rr == 0) ? SQ2 : (rr == 1 ? 1.0 : SQH);
  double shd = (rr == 0) ? SQH : (rr == 1 ? 1.0 : SQ2);
  float wf = (float)(S * swd), hf = (float)(S * shd);
  float ax1 = cx0 - 0.5f * wf, ay1 = cy0 - 0.5f * hf;
  float ax2 = cx0 + 0.5f * wf, ay2 = cy0 + 0.5f * hf;
  size_t base = (size_t)b * Al + i;
  float sc = prp[base * 2];
  float4 d4 = ((const float4*)rgp)[base];
  float dx = d4.x, dy = d4.y, dw = d4.z, dh = d4.w;
  float wa = ax2 - ax1, ha = ay2 - ay1;
  float cxa = ax1 + 0.5f * wa, cya = ay1 + 0.5f * ha;
  float cx = dx * wa + cxa, cy = dy * ha + cya;
  float w = (float)exp((double)dw) * wa;
  float h = (float)exp((double)dh) * ha;
  float x1 = cx - 0.5f * w, y1 = cy - 0.5f * h;
  float x2 = cx + 0.5f * w, y2 = cy + 0.5f * h;
  float Hc = P.info[b * 3 + 0] - 1.0f, Wc = P.info[b * 3 + 1] - 1.0f;
  float4 o;
  o.x = fminf(fmaxf(x1, 0.0f), Wc);
  o.y = fminf(fmaxf(y1, 0.0f), Hc);
  o.z = fminf(fmaxf(x2, 0.0f), Wc);
  o.w = fminf(fmaxf(y2, 0.0f), Hc);
  props[gid] = o;
  scores[gid] = sc;
}

// ---------------- Kernel 2a: 8-bit LDS-privatized histogram (fat blocks) ----------------
__global__ __launch_bounds__(256) void k_hist8(const float* __restrict__ scores,
                                               unsigned* __restrict__ hist8) {
  __shared__ unsigned h[256];
  int blk = blockIdx.x;
  int b = blk / HBLK, s = blk % HBLK;
  int l, seg; fatMap(s, l, seg);
  int n = lvlA(l), off = lvlOff(l);
  int start = seg * 4096;
  int cnt_s = min(4096, n - start);
  int tid = threadIdx.x;
  h[tid] = 0;
  __syncthreads();
  const float* sc = scores + (size_t)b * TOTA + off + start;
  for (int q = tid; q < cnt_s; q += 256)
    atomicAdd(&h[keyF(sc[q]) >> 24], 1u);
  __syncthreads();
  unsigned v = h[tid];
  if (v) atomicAdd(&hist8[(b * 5 + l) * 256 + tid], v);
}

// ---------------- Kernel 2b: find 8-bit bin + rank ----------------
__global__ __launch_bounds__(256) void k_thr8(const unsigned* __restrict__ hist8,
                                              unsigned* __restrict__ c1r1) {
  __shared__ unsigned h[256];
  int bl = blockIdx.x, tid = threadIdx.x;
  h[tid] = hist8[bl * 256 + tid];
  __syncthreads();
  if (tid == 0) {
    unsigned K = (unsigned)lvlK(bl % 5), cum = 0; int c;
    for (c = 255; c > 0; --c) { if (cum + h[c] >= K) break; cum += h[c]; }
    c1r1[bl * 2] = (unsigned)c;
    c1r1[bl * 2 + 1] = K - cum;
  }
}

// ---------------- Kernel 2c: 6-bit sub-histogram within c1 ----------------
__global__ __launch_bounds__(256) void k_hist6(const float* __restrict__ scores,
                                               const unsigned* __restrict__ c1r1,
                                               unsigned* __restrict__ hist6) {
  __shared__ unsigned h[64];
  int blk = blockIdx.x;
  int b = blk / HBLK, s = blk % HBLK;
  int l, seg; fatMap(s, l, seg);
  int n = lvlA(l), off = lvlOff(l);
  int start = seg * 4096;
  int cnt_s = min(4096, n - start);
  int tid = threadIdx.x;
  int bl = b * 5 + l;
  unsigned c1 = c1r1[bl * 2];
  if (tid < 64) h[tid] = 0;
  __syncthreads();
  const float* sc = scores + (size_t)b * TOTA + off + start;
  for (int q = tid; q < cnt_s; q += 256) {
    unsigned key = keyF(sc[q]);
    if ((key >> 24) == c1) atomicAdd(&h[(key >> 18) & 63u], 1u);
  }
  __syncthreads();
  if (tid < 64) {
    unsigned v = h[tid];
    if (v) atomicAdd(&hist6[bl * 64 + tid], v);
  }
}

// ---------------- Kernel 2d: final 14-bit threshold prefix ----------------
__global__ __launch_bounds__(64) void k_thr6(const unsigned* __restrict__ hist6,
                                             const unsigned* __restrict__ c1r1,
                                             unsigned* __restrict__ T14) {
  __shared__ unsigned h[64];
  int bl = blockIdx.x, tid = threadIdx.x;
  h[tid] = hist6[bl * 64 + tid];
  __syncthreads();
  if (tid == 0) {
    unsigned r1 = c1r1[bl * 2 + 1], cum = 0; int c;
    for (c = 63; c > 0; --c) { if (cum + h[c] >= r1) break; cum += h[c]; }
    T14[bl] = (c1r1[bl * 2] << 6) | (unsigned)c;
  }
}

// ---------------- Kernel 2e: per-block candidate count (no atomics) ----------------
__global__ __launch_bounds__(256) void k_cnt(const float* __restrict__ scores,
                                             const unsigned* __restrict__ T14,
                                             unsigned* __restrict__ blockCnt) {
  __shared__ unsigned ws[4];
  int gid = blockIdx.x * 256 + threadIdx.x;
  int tid = threadIdx.x;
  int b = gid / TOTA, ga = gid % TOTA;
  int l, off; gaToLvl(ga, l, off);
  int bl = b * 5 + l;
  bool pred = (keyF(scores[gid]) >> 18) >= T14[bl];
  unsigned long long m = __ballot(pred);
  if ((tid & 63) == 0) ws[tid >> 6] = (unsigned)__popcll(m);
  __syncthreads();
  if (tid == 0) blockCnt[blockIdx.x] = ws[0] + ws[1] + ws[2] + ws[3];
}

// ---------------- Kernel 2f: segmented exclusive scan of block counts ----------------
__global__ __launch_bounds__(1024) void k_scanblk(const unsigned* __restrict__ blockCnt,
                                                  unsigned* __restrict__ blockBase,
                                                  unsigned* __restrict__ cnt) {
  __shared__ unsigned a[4096];
  __shared__ unsigned ch[1024];
  int tid = threadIdx.x;
  int q0 = tid * 4;
  unsigned a0 = (q0 + 0 < NBLK) ? blockCnt[q0 + 0] : 0u;
  unsigned a1 = (q0 + 1 < NBLK) ? blockCnt[q0 + 1] : 0u;
  unsigned a2 = (q0 + 2 < NBLK) ? blockCnt[q0 + 2] : 0u;
  unsigned a3 = (q0 + 3 < NBLK) ? blockCnt[q0 + 3] : 0u;
  unsigned p0 = a0, p1 = p0 + a1, p2 = p1 + a2, p3 = p2 + a3;
  ch[tid] = p3;
  __syncthreads();
  for (int d = 1; d < 1024; d <<= 1) {
    unsigned t = (tid >= d) ? ch[tid - d] : 0u;
    __syncthreads();
    ch[tid] += t;
    __syncthreads();
  }
  unsigned cbase = (tid > 0) ? ch[tid - 1] : 0u;
  a[q0 + 0] = cbase + p0;
  a[q0 + 1] = cbase + p1;
  a[q0 + 2] = cbase + p2;
  a[q0 + 3] = cbase + p3;
  __syncthreads();
  for (int k = 0; k < 4; ++k) {
    int g = q0 + k;
    if (g < NBLK) {
      int b = g / BPB, r = g % BPB;
      int l = (r < 768) ? 0 : (r < 960) ? 1 : (r < 1008) ? 2 : (r < 1020) ? 3 : 4;
      int ss = b * BPB + lvlBlkStart(l);
      unsigned Eg = (g > 0) ? a[g - 1] : 0u;
      unsigned Es = (ss > 0) ? a[ss - 1] : 0u;
      blockBase[g] = Eg - Es;
    }
  }
  if (tid < NBL) {
    int b = tid / 5, l = tid % 5;
    int ss = b * BPB + lvlBlkStart(l);
    int ee = ss + lvlBlkCnt(l);
    unsigned Ee = a[ee - 1];
    unsigned Es = (ss > 0) ? a[ss - 1] : 0u;
    cnt[tid] = Ee - Es;
  }
}

// ---------------- Kernel 2g: fill candidates at deterministic positions ----------------
__global__ __launch_bounds__(256) void k_fill(const float* __restrict__ scores,
                                              const unsigned* __restrict__ T14,
                                              const unsigned* __restrict__ blockBase,
                                              unsigned long long* __restrict__ cand) {
  __shared__ unsigned ws[4];
  int gid = blockIdx.x * 256 + threadIdx.x;
  int tid = threadIdx.x;
  int b = gid / TOTA, ga = gid % TOTA;
  int l, off; gaToLvl(ga, l, off);
  int bl = b * 5 + l;
  unsigned key = keyF(scores[gid]);
  bool pred = (key >> 18) >= T14[bl];
  unsigned long long m = __ballot(pred);
  int wv = tid >> 6, ln = tid & 63;
  if (ln == 0) ws[wv] = (unsigned)__popcll(m);
  __syncthreads();
  unsigned wo = 0;
  for (int q = 0; q < wv; ++q) wo += ws[q];
  unsigned pre = (unsigned)__popcll(m & ((1ull << ln) - 1ull));
  if (pred) {
    unsigned p = blockBase[blockIdx.x] + wo + pre;
    if (p < CANDCAP)
      cand[(size_t)bl * CANDCAP + p] =
          ((unsigned long long)key << 32) | (unsigned long long)(0xFFFFFFFFu - (unsigned)(ga - off));
  }
}

// ---------------- Kernel 2h: sort each 512-chunk of candidates (bitonic in LDS) ----------------
__global__ __launch_bounds__(256) void k_sortc(unsigned long long* __restrict__ cand,
                                               const unsigned* __restrict__ cnt) {
  __shared__ unsigned long long arr[512];
  int blk = blockIdx.x;
  int bl = blk >> 3, ch = blk & 7;
  int base = ch * 512;
  int num = (int)min(cnt[bl], (unsigned)CANDCAP);
  int tid = threadIdx.x;
  unsigned long long* cp = cand + (size_t)bl * CANDCAP + base;
  for (int q = tid; q < 512; q += 256)
    arr[q] = (base + q < num) ? cp[q] : 0ull;
  __syncthreads();
  for (int kk = 2; kk <= 512; kk <<= 1)
    for (int jj = kk >> 1; jj > 0; jj >>= 1) {
      for (int idx = tid; idx < 512; idx += 256) {
        int p2 = idx ^ jj;
        if (p2 > idx) {
          unsigned long long x = arr[idx], y = arr[p2];
          bool up = (idx & kk) == 0;
          if (up ? (x < y) : (x > y)) { arr[idx] = y; arr[p2] = x; }
        }
      }
      __syncthreads();
    }
  for (int q = tid; q < 512; q += 256) cp[q] = arr[q];  // write back pads too (determinism)
}

// ---------------- Kernel 2i: merge-rank scatter into sorted top-K ----------------
__global__ __launch_bounds__(256) void k_rank(const unsigned long long* __restrict__ cand,
                                              const float4* __restrict__ props,
                                              const float* __restrict__ scores,
                                              float4* __restrict__ sBox,
                                              float* __restrict__ sScore) {
  int gid = blockIdx.x * 256 + threadIdx.x;
  int bl = gid >> 12, p = gid & 4095;
  int b = bl / 5, l = bl % 5;
  int K = lvlK(l), off = lvlOff(l);
  const unsigned long long* cp = cand + (size_t)bl * CANDCAP;
  unsigned long long me = cp[p];
  int ch = p >> 9;
  int rank = p & 511;  // index within own sorted chunk = # larger (keys unique)
  for (int c2 = 0; c2 < 8; ++c2) {
    if (c2 == ch) continue;
    const unsigned long long* d = cp + c2 * 512;
    int lo = 0, hi = 512;
    while (lo < hi) {
      int mid = (lo + hi) >> 1;
      if (d[mid] > me) lo = mid + 1; else hi = mid;
    }
    rank += lo;
  }
  if (rank < K) {
    unsigned idx = 0xFFFFFFFFu - (unsigned)(me & 0xFFFFFFFFull);
    float4 bx = props[(size_t)b * TOTA + off + idx];
    sBox[bl * PRE + rank] = bx;
    sScore[bl * PRE + rank] = scores[(size_t)b * TOTA + off + idx];
  }
}

// ---------------- Kernel 3: IoU bitmask — i-threaded, wave-uniform j window ----------------
// Block = (bl, 64-i-tile ic, 256-j-chunk jc). Thread tid -> i = ic*64 + (tid&63),
// word wsub = tid>>6. Wave w's 64 lanes all read jb[w*64+t] at a WAVE-UNIFORM
// address (HW broadcast, zero conflicts); each lane holds its own i-box in regs
// and builds its 64-bit word via shift-or. Areas computed inline from boxes
// (bit-identical to fmax(z-x,0)*fmax(w-y,0)) — no ja array / no ds_read_b32.
// Diagonal word (jw==ic) additionally stored compactly to diagBuf for k_nms.
__global__ __launch_bounds__(256) void k_mask(const float4* __restrict__ sBox,
                                              unsigned long long* __restrict__ mask,
                                              unsigned long long* __restrict__ diagBuf) {
  int bi = blockIdx.x;
  int bl = bi >> 8, rem = bi & 255, ic = rem >> 3, jc = rem & 7;
  int l = bl % 5, K = lvlK(l);
  int i0 = ic * 64, j0 = jc * 256;
  if (i0 >= K || j0 >= K) return;
  if (jc * 4 + 3 < ic) return;  // all words jw < ic: never read by k_nms
  int tid = threadIdx.x;
  __shared__ float4 jb[256];
  int jend = min(256, K - j0);
  if (tid < jend) jb[tid] = sBox[bl * PRE + j0 + tid];
  int ln = tid & 63, wsub = tid >> 6;
  int i = i0 + ln;
  int jw = jc * 4 + wsub;
  bool iv = i < K;
  float4 bi4 = make_float4(0.0f, 0.0f, 0.0f, 0.0f);
  if (iv) bi4 = sBox[bl * PRE + i];
  float ai = fmaxf(bi4.z - bi4.x, 0.0f) * fmaxf(bi4.w - bi4.y, 0.0f);
  __syncthreads();
  int jbase = wsub * 64;
  int lim = jend - jbase;          // may be <= 0 (word beyond K: never read)
  if (lim > 64) lim = 64;
  unsigned long long wacc = 0ull;
#pragma unroll 4
  for (int t = 0; t < lim; ++t) {
    float4 b4 = jb[jbase + t];     // wave-uniform -> broadcast
    float aj = fmaxf(b4.z - b4.x, 0.0f) * fmaxf(b4.w - b4.y, 0.0f);
    int j = j0 + jbase + t;
    bool pred = false;
    if (j > i) {
      float ltx = fmaxf(bi4.x, b4.x), lty = fmaxf(bi4.y, b4.y);
      float rbx = fminf(bi4.z, b4.z), rby = fminf(bi4.w, b4.w);
      float wx = fmaxf(rbx - ltx, 0.0f), wy = fmaxf(rby - lty, 0.0f);
      float inter = wx * wy;
      float den = fmaxf(ai + aj - inter, 1e-9f);
      pred = (inter / den) > 0.7f;
    }
    wacc |= ((unsigned long long)(pred ? 1u : 0u)) << t;
  }
  if (iv && jw >= ic && lim > 0) {
    mask[((size_t)bl * PRE + i) * 32 + jw] = wacc;
    if (jw == ic) diagBuf[(size_t)bl * PRE + i] = wacc;
  }
}

// ---------------- Kernel 4: tile NMS — ff1 chain + depth-2 A/B prefetch ----------------
__global__ __launch_bounds__(1024) void k_nms(const unsigned long long* __restrict__ mask,
                                              const unsigned long long* __restrict__ diagBuf,
                                              const float4* __restrict__ sBox,
                                              const float* __restrict__ sScore,
                                              float* __restrict__ catScore,
                                              float4* __restrict__ catBox) {
  __shared__ unsigned long long diag[PRE];
  __shared__ unsigned long long remv[32];
  __shared__ int list[1000];
  __shared__ int sTotal;
  int bl = blockIdx.x, b = bl / 5, l = bl % 5;
  int K = lvlK(l), KP = lvlKP(l), co = l * 1000;
  int tid = threadIdx.x;
  const unsigned long long* mrow = mask + (size_t)bl * PRE * 32;
  int c = tid & 31, g = tid >> 5;
  int nw = (K + 63) >> 6;
  for (int r = tid; r < K; r += 1024) diag[r] = diagBuf[(size_t)bl * PRE + r];
  if (tid < 32) remv[tid] = 0ull;
  __syncthreads();

#define NMS_ISSUE(T, X0, X1)                                         \
  {                                                                  \
    X0 = 0ull; X1 = 0ull;                                            \
    int _t = (T);                                                    \
    if (_t < nw) {                                                   \
      bool _act = (c > _t) && (c < nw);                              \
      int _r0 = _t * 64 + g, _r1 = _r0 + 32;                         \
      if (_act && _r0 < K) X0 = mrow[(size_t)_r0 * 32 + c];          \
      if (_act && _r1 < K) X1 = mrow[(size_t)_r1 * 32 + c];          \
    }                                                                \
  }

#define NMS_CHAIN(T)                                                 \
  if (tid < 64) {                                                    \
    int _t = (T);                                                    \
    int _dr = _t * 64 + tid;                                         \
    unsigned long long _d = (_dr < K) ? diag[_dr] : 0ull;            \
    unsigned long long _local = remv[_t];                            \
    int _lim = min(64, K - _t * 64);                                 \
    unsigned long long _vm = (_lim >= 64) ? ~0ull : ((1ull << _lim) - 1ull); \
    unsigned long long _todo = (~_local) & _vm;                      \
    while (_todo) {                                                  \
      int _i2 = __ffsll((long long)_todo) - 1;                       \
      unsigned _lo = __builtin_amdgcn_readlane((unsigned)_d, _i2);   \
      unsigned _hi = __builtin_amdgcn_readlane((unsigned)(_d >> 32), _i2); \
      unsigned long long _dd = ((unsigned long long)_hi << 32) | (unsigned long long)_lo; \
      _local |= _dd;                                                 \
      _todo &= ~_dd;                                                 \
      _todo &= ~(1ull << _i2);                                       \
    }                                                                \
    if (tid == 0) remv[_t] = _local;                                 \
  }

#define NMS_OR(T, X0, X1)                                            \
  {                                                                  \
    int _t = (T);                                                    \
    unsigned long long _local = remv[_t];                            \
    bool _act = (c > _t) && (c < nw);                                \
    if (_act) {                                                      \
      unsigned long long _acc = 0ull;                                \
      int _r0 = _t * 64 + g, _r1 = _r0 + 32;                         \
      if (_r0 < K && !((_local >> g) & 1ull)) _acc |= X0;            \
      if (_r1 < K && !((_local >> (g + 32)) & 1ull)) _acc |= X1;     \
      if (_acc) atomicOr(&remv[c], _acc);                            \
    }                                                                \
  }

  unsigned long long a0, a1, b0, b1;
  NMS_ISSUE(0, a0, a1)
  NMS_ISSUE(1, b0, b1)
  for (int t = 0; t < nw; t += 2) {
    NMS_CHAIN(t)
    __syncthreads();
    NMS_OR(t, a0, a1)
    NMS_ISSUE(t + 2, a0, a1)
    __syncthreads();
    if (t + 1 < nw) {
      NMS_CHAIN(t + 1)
      __syncthreads();
      NMS_OR(t + 1, b0, b1)
      NMS_ISSUE(t + 3, b0, b1)
      __syncthreads();
    }
  }
#undef NMS_ISSUE
#undef NMS_CHAIN
#undef NMS_OR

  if (tid < 64) {
    int lane = tid;
    bool lv = lane < 32;
    unsigned long long remw = lv ? remv[lane] : 0ull;
    unsigned long long valid = 0ull;
    if (lv) {
      int rem = K - lane * 64;
      valid = (rem >= 64) ? ~0ull : (rem <= 0 ? 0ull : ((1ull << rem) - 1ull));
    }
    unsigned long long keepw = (~remw) & valid;
    unsigned long long suppw = remw & valid;
    unsigned long long lmask = (1ull << lane) - 1ull;
    int base = 0;
    for (int w2 = 0; w2 < 32 && base < KP; ++w2) {
      unsigned long long word = __shfl(keepw, w2);
      int pre = __popcll(word & lmask);
      if (((word >> lane) & 1ull) && (base + pre) < KP) list[base + pre] = w2 * 64 + lane;
      base += __popcll(word);
    }
    int totalKept = base;
    if (totalKept < KP) {
      int b2 = totalKept;
      for (int w2 = 0; w2 < 32 && b2 < KP; ++w2) {
        unsigned long long word = __shfl(suppw, w2);
        int pre = __popcll(word & lmask);
        if (((word >> lane) & 1ull) && (b2 + pre) < KP) list[b2 + pre] = w2 * 64 + lane;
        b2 += __popcll(word);
      }
    }
    if (lane == 0) sTotal = totalKept;
  }
  __syncthreads();
  int totalKept = sTotal;
  for (int t = tid; t < KP; t += 1024) {
    int j = list[t];
    float s = (t < totalKept) ? sScore[bl * PRE + j] : -1.0f;
    catScore[b * CATN + co + t] = s;
    catBox[b * CATN + co + t] = sBox[bl * PRE + j];
  }
}

// ---------------- Kernel 5: final top-1000 via 5-way merge rank ----------------
__global__ __launch_bounds__(256) void k_final(const float* __restrict__ catScore,
                                               const float4* __restrict__ catBox,
                                               float* __restrict__ out) {
  int gid = blockIdx.x * 256 + threadIdx.x;
  if (gid >= NB * CATN) return;
  int b = gid / CATN, p = gid % CATN;
  int c = p / 1000; if (c > 4) c = 4;
  const float* cs = catScore + (size_t)b * CATN;
  float s = cs[p];
  unsigned long long me = ((unsigned long long)keyF(s) << 32) |
                          (unsigned long long)(0xFFFFFFFFu - (unsigned)p);
  int rank = p - c * 1000;
  for (int c2 = 0; c2 < 5; ++c2) {
    if (c2 == c) continue;
    int base = c2 * 1000, len = (c2 == 4) ? 768 : 1000;
    int lo = 0, hi = len;
    while (lo < hi) {
      int mid = (lo + hi) >> 1;
      int q = base + mid;
      unsigned long long k2 = ((unsigned long long)keyF(cs[q]) << 32) |
                              (unsigned long long)(0xFFFFFFFFu - (unsigned)q);
      if (k2 > me) lo = mid + 1; else hi = mid;
    }
    rank += lo;
  }
  if (rank < POST) {
    float4 bx = make_float4(0.0f, 0.0f, 0.0f, 0.0f);
    if (s >= 0.0f) bx = catBox[(size_t)b * CATN + p];
    float* o = out + ((size_t)b * POST + rank) * 5;
    o[0] = (float)b; o[1] = bx.x; o[2] = bx.y; o[3] = bx.z; o[4] = bx.w;
  }
}

extern "C" void kernel_launch(void* const* d_in, const int* in_sizes, int n_in,
                              void* d_out, int out_size, void* d_ws, size_t ws_size,
                              hipStream_t stream) {
  const int prSz[5] = {1572864, 393216, 98304, 24576, 6144};
  const int rgSz[5] = {3145728, 786432, 196608, 49152, 12288};
  const float* pr[5] = {nullptr, nullptr, nullptr, nullptr, nullptr};
  const float* rg[5] = {nullptr, nullptr, nullptr, nullptr, nullptr};
  const float* info = nullptr;
  for (int i = 0; i < n_in; ++i) {
    int s = in_sizes[i];
    bool m = false;
    for (int l = 0; l < 5; ++l) {
      if (s == prSz[l]) { pr[l] = (const float*)d_in[i]; m = true; break; }
      if (s == rgSz[l]) { rg[l] = (const float*)d_in[i]; m = true; break; }
    }
    if (!m && s == 12) info = (const float*)d_in[i];
  }
  InPtrs P;
  P.p0 = pr[0]; P.p1 = pr[1]; P.p2 = pr[2]; P.p3 = pr[3]; P.p4 = pr[4];
  P.r0 = rg[0]; P.r1 = rg[1]; P.r2 = rg[2]; P.r3 = rg[3]; P.r4 = rg[4];
  P.info = info;

  char* w = (char*)d_ws;
  float4* props = (float4*)w;                         w += (size_t)NB * TOTA * 16;
  float4* sBox = (float4*)w;                          w += (size_t)NBL * PRE * 16;
  float4* catBox = (float4*)w;                        w += (size_t)NB * CATN * 16;
  unsigned long long* mask = (unsigned long long*)w;  w += (size_t)NBL * PRE * 32 * 8;
  unsigned long long* cand = (unsigned long long*)w;  w += (size_t)NBL * CANDCAP * 8;
  unsigned long long* diagBuf = (unsigned long long*)w; w += (size_t)NBL * PRE * 8;
  float* scores = (float*)w;                          w += (size_t)NB * TOTA * 4;
  float* sScore = (float*)w;                          w += (size_t)NBL * PRE * 4;
  float* catScore = (float*)w;                        w += (size_t)NB * CATN * 4;
  unsigned* hist8 = (unsigned*)w;                     w += (size_t)NBL * 256 * 4;
  unsigned* hist6 = (unsigned*)w;                     w += (size_t)NBL * 64 * 4;
  unsigned* c1r1 = (unsigned*)w;                      w += (size_t)NBL * 2 * 4;
  unsigned* T14 = (unsigned*)w;                       w += (size_t)NBL * 4;
  unsigned* blockCnt = (unsigned*)w;                  w += (size_t)NBLK * 4;
  unsigned* blockBase = (unsigned*)w;                 w += (size_t)NBLK * 4;
  unsigned* cnt = (unsigned*)w;                       w += (size_t)NBL * 4;
  (void)ws_size; (void)out_size;

  hipMemsetAsync(hist8, 0, (size_t)NBL * (256 + 64) * 4, stream);

  k_decode<<<(NB * TOTA + 255) / 256, 256, 0, stream>>>(P, props, scores);
  k_hist8<<<NB * HBLK, 256, 0, stream>>>(scores, hist8);
  k_thr8<<<NBL, 256, 0, stream>>>(hist8, c1r1);
  k_hist6<<<NB * HBLK, 256, 0, stream>>>(scores, c1r1, hist6);
  k_thr6<<<NBL, 64, 0, stream>>>(hist6, c1r1, T14);
  k_cnt<<<NBLK, 256, 0, stream>>>(scores, T14, blockCnt);
  k_scanblk<<<1, 1024, 0, stream>>>(blockCnt, blockBase, cnt);
  k_fill<<<NBLK, 256, 0, stream>>>(scores, T14, blockBase, cand);
  k_sortc<<<NBL * 8, 256, 0, stream>>>(cand, cnt);
  k_rank<<<NBL * CANDCAP / 256, 256, 0, stream>>>(cand, props, scores, sBox, sScore);
  k_mask<<<NBL * 256, 256, 0, stream>>>(sBox, mask, diagBuf);
  k_nms<<<NBL, 1024, 0, stream>>>(mask, diagBuf, sBox, sScore, catScore, catBox);
  k_final<<<(NB * CATN + 255) / 256, 256, 0, stream>>>(catScore, catBox, (float*)d_out);
}

// Round 19
// 195.074 us; speedup vs baseline: 2.3136x; 1.0418x over previous
//
#include <hip/hip_runtime.h>
#include <stdint.h>
#include <math.h>

#pragma clang fp contract(off)

#define NB 4
#define TOTA 261888
#define PRE 2000
#define POST 1000
#define CATN 4768
#define NBL 20
#define CANDCAP 4096
#define NBLK 4092          // NB * TOTA / 256
#define BPB 1023           // blocks per image (TOTA/256)
#define HBLK 65            // fat hist blocks per image: 48+12+3+1+1

// Exact round-boundary for (RN32(inter/den) > 0.7f):
// boundary m = 0.7f + 2^-25 (tie at m rounds to even = 0x3F333334 > 0.7f, inclusive).
// m has 25 sig bits, den has <=24 -> m*(double)den exact; comparison is bit-exact.
#define IOU_M (0.699999988079071044921875 + 0x1.0p-25)

__device__ __forceinline__ unsigned keyF(float f) {
  unsigned u = __float_as_uint(f);
  return (u & 0x80000000u) ? ~u : (u | 0x80000000u);
}

__device__ __forceinline__ int lvlA(int l)   { switch (l) { case 0: return 196608; case 1: return 49152; case 2: return 12288; case 3: return 3072; default: return 768; } }
__device__ __forceinline__ int lvlOff(int l) { switch (l) { case 0: return 0; case 1: return 196608; case 2: return 245760; case 3: return 258048; default: return 261120; } }
__device__ __forceinline__ int lvlK(int l)   { return l == 4 ? 768 : 2000; }
__device__ __forceinline__ int lvlKP(int l)  { return l == 4 ? 768 : 1000; }
__device__ __forceinline__ int lvlBlkStart(int l) { switch (l) { case 0: return 0; case 1: return 768; case 2: return 960; case 3: return 1008; default: return 1020; } }
__device__ __forceinline__ int lvlBlkCnt(int l)   { switch (l) { case 0: return 768; case 1: return 192; case 2: return 48; case 3: return 12; default: return 3; } }

struct InPtrs {
  const float *p0, *p1, *p2, *p3, *p4;
  const float *r0, *r1, *r2, *r3, *r4;
  const float *info;
};

__device__ __forceinline__ void gaToLvl(int ga, int& l, int& off) {
  if (ga < 196608)      { l = 0; off = 0; }
  else if (ga < 245760) { l = 1; off = 196608; }
  else if (ga < 258048) { l = 2; off = 245760; }
  else if (ga < 261120) { l = 3; off = 258048; }
  else                  { l = 4; off = 261120; }
}

__device__ __forceinline__ void fatMap(int s, int& l, int& seg) {
  if (s < 48)      { l = 0; seg = s; }
  else if (s < 60) { l = 1; seg = s - 48; }
  else if (s < 63) { l = 2; seg = s - 60; }
  else if (s == 63){ l = 3; seg = 0; }
  else             { l = 4; seg = 0; }
}

// ---------------- Kernel 1: decode + clip + score extract ----------------
__global__ __launch_bounds__(256) void k_decode(InPtrs P, float4* __restrict__ props,
                                                float* __restrict__ scores) {
  int gid = blockIdx.x * 256 + threadIdx.x;
  if (gid >= NB * TOTA) return;
  int b = gid / TOTA, ga = gid % TOTA;
  int Al, off, lg; float st; double S; const float *prp, *rgp;
  if (ga < 196608)      { Al = 196608; off = 0;      lg = 8; st = 4.0f;  S = 256.0;  prp = P.p0; rgp = P.r0; }
  else if (ga < 245760) { Al = 49152;  off = 196608; lg = 7; st = 8.0f;  S = 512.0;  prp = P.p1; rgp = P.r1; }
  else if (ga < 258048) { Al = 12288;  off = 245760; lg = 6; st = 16.0f; S = 1024.0; prp = P.p2; rgp = P.r2; }
  else if (ga < 261120) { Al = 3072;   off = 258048; lg = 5; st = 32.0f; S = 2048.0; prp = P.p3; rgp = P.r3; }
  else                  { Al = 768;    off = 261120; lg = 4; st = 64.0f; S = 4096.0; prp = P.p4; rgp = P.r4; }
  int i = ga - off;
  int cell = i / 3, rr = i - cell * 3;
  int col = cell & ((1 << lg) - 1), row = cell >> lg;
  float cx0 = ((float)col + 0.5f) * st;
  float cy0 = ((float)row + 0.5f) * st;
  const double SQ2 = 1.4142135623730951;
  const double SQH = 0.7071067811865476;
  double swd = (rr == 0) ? SQ2 : (rr == 1 ? 1.0 : SQH);
  double shd = (rr == 0) ? SQH : (rr == 1 ? 1.0 : SQ2);
  float wf = (float)(S * swd), hf = (float)(S * shd);
  float ax1 = cx0 - 0.5f * wf, ay1 = cy0 - 0.5f * hf;
  float ax2 = cx0 + 0.5f * wf, ay2 = cy0 + 0.5f * hf;
  size_t base = (size_t)b * Al + i;
  float sc = prp[base * 2];
  float4 d4 = ((const float4*)rgp)[base];
  float dx = d4.x, dy = d4.y, dw = d4.z, dh = d4.w;
  float wa = ax2 - ax1, ha = ay2 - ay1;
  float cxa = ax1 + 0.5f * wa, cya = ay1 + 0.5f * ha;
  float cx = dx * wa + cxa, cy = dy * ha + cya;
  float w = (float)exp((double)dw) * wa;
  float h = (float)exp((double)dh) * ha;
  float x1 = cx - 0.5f * w, y1 = cy - 0.5f * h;
  float x2 = cx + 0.5f * w, y2 = cy + 0.5f * h;
  float Hc = P.info[b * 3 + 0] - 1.0f, Wc = P.info[b * 3 + 1] - 1.0f;
  float4 o;
  o.x = fminf(fmaxf(x1, 0.0f), Wc);
  o.y = fminf(fmaxf(y1, 0.0f), Hc);
  o.z = fminf(fmaxf(x2, 0.0f), Wc);
  o.w = fminf(fmaxf(y2, 0.0f), Hc);
  props[gid] = o;
  scores[gid] = sc;
}

// ---------------- Kernel 2a: 8-bit LDS-privatized histogram (fat blocks) ----------------
__global__ __launch_bounds__(256) void k_hist8(const float* __restrict__ scores,
                                               unsigned* __restrict__ hist8) {
  __shared__ unsigned h[256];
  int blk = blockIdx.x;
  int b = blk / HBLK, s = blk % HBLK;
  int l, seg; fatMap(s, l, seg);
  int n = lvlA(l), off = lvlOff(l);
  int start = seg * 4096;
  int cnt_s = min(4096, n - start);
  int tid = threadIdx.x;
  h[tid] = 0;
  __syncthreads();
  const float* sc = scores + (size_t)b * TOTA + off + start;
  for (int q = tid; q < cnt_s; q += 256)
    atomicAdd(&h[keyF(sc[q]) >> 24], 1u);
  __syncthreads();
  unsigned v = h[tid];
  if (v) atomicAdd(&hist8[(b * 5 + l) * 256 + tid], v);
}

// ---------------- Kernel 2b: find 8-bit bin + rank ----------------
__global__ __launch_bounds__(256) void k_thr8(const unsigned* __restrict__ hist8,
                                              unsigned* __restrict__ c1r1) {
  __shared__ unsigned h[256];
  int bl = blockIdx.x, tid = threadIdx.x;
  h[tid] = hist8[bl * 256 + tid];
  __syncthreads();
  if (tid == 0) {
    unsigned K = (unsigned)lvlK(bl % 5), cum = 0; int c;
    for (c = 255; c > 0; --c) { if (cum + h[c] >= K) break; cum += h[c]; }
    c1r1[bl * 2] = (unsigned)c;
    c1r1[bl * 2 + 1] = K - cum;
  }
}

// ---------------- Kernel 2c: 6-bit sub-histogram within c1 ----------------
__global__ __launch_bounds__(256) void k_hist6(const float* __restrict__ scores,
                                               const unsigned* __restrict__ c1r1,
                                               unsigned* __restrict__ hist6) {
  __shared__ unsigned h[64];
  int blk = blockIdx.x;
  int b = blk / HBLK, s = blk % HBLK;
  int l, seg; fatMap(s, l, seg);
  int n = lvlA(l), off = lvlOff(l);
  int start = seg * 4096;
  int cnt_s = min(4096, n - start);
  int tid = threadIdx.x;
  int bl = b * 5 + l;
  unsigned c1 = c1r1[bl * 2];
  if (tid < 64) h[tid] = 0;
  __syncthreads();
  const float* sc = scores + (size_t)b * TOTA + off + start;
  for (int q = tid; q < cnt_s; q += 256) {
    unsigned key = keyF(sc[q]);
    if ((key >> 24) == c1) atomicAdd(&h[(key >> 18) & 63u], 1u);
  }
  __syncthreads();
  if (tid < 64) {
    unsigned v = h[tid];
    if (v) atomicAdd(&hist6[bl * 64 + tid], v);
  }
}

// ---------------- Kernel 2d: final 14-bit threshold prefix ----------------
__global__ __launch_bounds__(64) void k_thr6(const unsigned* __restrict__ hist6,
                                             const unsigned* __restrict__ c1r1,
                                             unsigned* __restrict__ T14) {
  __shared__ unsigned h[64];
  int bl = blockIdx.x, tid = threadIdx.x;
  h[tid] = hist6[bl * 64 + tid];
  __syncthreads();
  if (tid == 0) {
    unsigned r1 = c1r1[bl * 2 + 1], cum = 0; int c;
    for (c = 63; c > 0; --c) { if (cum + h[c] >= r1) break; cum += h[c]; }
    T14[bl] = (c1r1[bl * 2] << 6) | (unsigned)c;
  }
}

// ---------------- Kernel 2e: per-block candidate count (no atomics) ----------------
__global__ __launch_bounds__(256) void k_cnt(const float* __restrict__ scores,
                                             const unsigned* __restrict__ T14,
                                             unsigned* __restrict__ blockCnt) {
  __shared__ unsigned ws[4];
  int gid = blockIdx.x * 256 + threadIdx.x;
  int tid = threadIdx.x;
  int b = gid / TOTA, ga = gid % TOTA;
  int l, off; gaToLvl(ga, l, off);
  int bl = b * 5 + l;
  bool pred = (keyF(scores[gid]) >> 18) >= T14[bl];
  unsigned long long m = __ballot(pred);
  if ((tid & 63) == 0) ws[tid >> 6] = (unsigned)__popcll(m);
  __syncthreads();
  if (tid == 0) blockCnt[blockIdx.x] = ws[0] + ws[1] + ws[2] + ws[3];
}

// ---------------- Kernel 2f: segmented exclusive scan of block counts ----------------
__global__ __launch_bounds__(1024) void k_scanblk(const unsigned* __restrict__ blockCnt,
                                                  unsigned* __restrict__ blockBase,
                                                  unsigned* __restrict__ cnt) {
  __shared__ unsigned a[4096];
  __shared__ unsigned ch[1024];
  int tid = threadIdx.x;
  int q0 = tid * 4;
  unsigned a0 = (q0 + 0 < NBLK) ? blockCnt[q0 + 0] : 0u;
  unsigned a1 = (q0 + 1 < NBLK) ? blockCnt[q0 + 1] : 0u;
  unsigned a2 = (q0 + 2 < NBLK) ? blockCnt[q0 + 2] : 0u;
  unsigned a3 = (q0 + 3 < NBLK) ? blockCnt[q0 + 3] : 0u;
  unsigned p0 = a0, p1 = p0 + a1, p2 = p1 + a2, p3 = p2 + a3;
  ch[tid] = p3;
  __syncthreads();
  for (int d = 1; d < 1024; d <<= 1) {
    unsigned t = (tid >= d) ? ch[tid - d] : 0u;
    __syncthreads();
    ch[tid] += t;
    __syncthreads();
  }
  unsigned cbase = (tid > 0) ? ch[tid - 1] : 0u;
  a[q0 + 0] = cbase + p0;
  a[q0 + 1] = cbase + p1;
  a[q0 + 2] = cbase + p2;
  a[q0 + 3] = cbase + p3;
  __syncthreads();
  for (int k = 0; k < 4; ++k) {
    int g = q0 + k;
    if (g < NBLK) {
      int b = g / BPB, r = g % BPB;
      int l = (r < 768) ? 0 : (r < 960) ? 1 : (r < 1008) ? 2 : (r < 1020) ? 3 : 4;
      int ss = b * BPB + lvlBlkStart(l);
      unsigned Eg = (g > 0) ? a[g - 1] : 0u;
      unsigned Es = (ss > 0) ? a[ss - 1] : 0u;
      blockBase[g] = Eg - Es;
    }
  }
  if (tid < NBL) {
    int b = tid / 5, l = tid % 5;
    int ss = b * BPB + lvlBlkStart(l);
    int ee = ss + lvlBlkCnt(l);
    unsigned Ee = a[ee - 1];
    unsigned Es = (ss > 0) ? a[ss - 1] : 0u;
    cnt[tid] = Ee - Es;
  }
}

// ---------------- Kernel 2g: fill candidates at deterministic positions ----------------
__global__ __launch_bounds__(256) void k_fill(const float* __restrict__ scores,
                                              const unsigned* __restrict__ T14,
                                              const unsigned* __restrict__ blockBase,
                                              unsigned long long* __restrict__ cand) {
  __shared__ unsigned ws[4];
  int gid = blockIdx.x * 256 + threadIdx.x;
  int tid = threadIdx.x;
  int b = gid / TOTA, ga = gid % TOTA;
  int l, off; gaToLvl(ga, l, off);
  int bl = b * 5 + l;
  unsigned key = keyF(scores[gid]);
  bool pred = (key >> 18) >= T14[bl];
  unsigned long long m = __ballot(pred);
  int wv = tid >> 6, ln = tid & 63;
  if (ln == 0) ws[wv] = (unsigned)__popcll(m);
  __syncthreads();
  unsigned wo = 0;
  for (int q = 0; q < wv; ++q) wo += ws[q];
  unsigned pre = (unsigned)__popcll(m & ((1ull << ln) - 1ull));
  if (pred) {
    unsigned p = blockBase[blockIdx.x] + wo + pre;
    if (p < CANDCAP)
      cand[(size_t)bl * CANDCAP + p] =
          ((unsigned long long)key << 32) | (unsigned long long)(0xFFFFFFFFu - (unsigned)(ga - off));
  }
}

// ---------------- Kernel 2h: sort each 512-chunk of candidates (bitonic in LDS) ----------------
__global__ __launch_bounds__(256) void k_sortc(unsigned long long* __restrict__ cand,
                                               const unsigned* __restrict__ cnt) {
  __shared__ unsigned long long arr[512];
  int blk = blockIdx.x;
  int bl = blk >> 3, ch = blk & 7;
  int base = ch * 512;
  int num = (int)min(cnt[bl], (unsigned)CANDCAP);
  int tid = threadIdx.x;
  unsigned long long* cp = cand + (size_t)bl * CANDCAP + base;
  for (int q = tid; q < 512; q += 256)
    arr[q] = (base + q < num) ? cp[q] : 0ull;
  __syncthreads();
  for (int kk = 2; kk <= 512; kk <<= 1)
    for (int jj = kk >> 1; jj > 0; jj >>= 1) {
      for (int idx = tid; idx < 512; idx += 256) {
        int p2 = idx ^ jj;
        if (p2 > idx) {
          unsigned long long x = arr[idx], y = arr[p2];
          bool up = (idx & kk) == 0;
          if (up ? (x < y) : (x > y)) { arr[idx] = y; arr[p2] = x; }
        }
      }
      __syncthreads();
    }
  for (int q = tid; q < 512; q += 256) cp[q] = arr[q];  // write back pads too (determinism)
}

// ---------------- Kernel 2i: merge-rank scatter into sorted top-K ----------------
__global__ __launch_bounds__(256) void k_rank(const unsigned long long* __restrict__ cand,
                                              const float4* __restrict__ props,
                                              const float* __restrict__ scores,
                                              float4* __restrict__ sBox,
                                              float* __restrict__ sScore) {
  int gid = blockIdx.x * 256 + threadIdx.x;
  int bl = gid >> 12, p = gid & 4095;
  int b = bl / 5, l = bl % 5;
  int K = lvlK(l), off = lvlOff(l);
  const unsigned long long* cp = cand + (size_t)bl * CANDCAP;
  unsigned long long me = cp[p];
  int ch = p >> 9;
  int rank = p & 511;  // index within own sorted chunk = # larger (keys unique)
  for (int c2 = 0; c2 < 8; ++c2) {
    if (c2 == ch) continue;
    const unsigned long long* d = cp + c2 * 512;
    int lo = 0, hi = 512;
    while (lo < hi) {
      int mid = (lo + hi) >> 1;
      if (d[mid] > me) lo = mid + 1; else hi = mid;
    }
    rank += lo;
  }
  if (rank < K) {
    unsigned idx = 0xFFFFFFFFu - (unsigned)(me & 0xFFFFFFFFull);
    float4 bx = props[(size_t)b * TOTA + off + idx];
    sBox[bl * PRE + rank] = bx;
    sScore[bl * PRE + rank] = scores[(size_t)b * TOTA + off + idx];
  }
}

// ---------------- Kernel 3: IoU bitmask — i-threaded, wave-uniform j window ----------------
// Block = (bl, 64-i-tile ic, 256-j-chunk jc). Thread tid -> i = ic*64 + (tid&63),
// word wsub = tid>>6. Wave w's 64 lanes all read jb[w*64+t] at a WAVE-UNIFORM
// address (HW broadcast, zero conflicts); each lane holds its own i-box in regs
// and builds its 64-bit word via shift-or. The IoU>0.7 test uses the EXACT
// double multiply-compare (see IOU_M) — bit-identical to the f32 division,
// ~6 fewer VALU instructions per eval. Areas computed inline from boxes.
// Diagonal word (jw==ic) additionally stored compactly to diagBuf for k_nms.
__global__ __launch_bounds__(256) void k_mask(const float4* __restrict__ sBox,
                                              unsigned long long* __restrict__ mask,
                                              unsigned long long* __restrict__ diagBuf) {
  int bi = blockIdx.x;
  int bl = bi >> 8, rem = bi & 255, ic = rem >> 3, jc = rem & 7;
  int l = bl % 5, K = lvlK(l);
  int i0 = ic * 64, j0 = jc * 256;
  if (i0 >= K || j0 >= K) return;
  if (jc * 4 + 3 < ic) return;  // all words jw < ic: never read by k_nms
  int tid = threadIdx.x;
  __shared__ float4 jb[256];
  int jend = min(256, K - j0);
  if (tid < jend) jb[tid] = sBox[bl * PRE + j0 + tid];
  int ln = tid & 63, wsub = tid >> 6;
  int i = i0 + ln;
  int jw = jc * 4 + wsub;
  bool iv = i < K;
  float4 bi4 = make_float4(0.0f, 0.0f, 0.0f, 0.0f);
  if (iv) bi4 = sBox[bl * PRE + i];
  float ai = fmaxf(bi4.z - bi4.x, 0.0f) * fmaxf(bi4.w - bi4.y, 0.0f);
  __syncthreads();
  int jbase = wsub * 64;
  int lim = jend - jbase;          // may be <= 0 (word beyond K: never read)
  if (lim > 64) lim = 64;
  unsigned long long wacc = 0ull;
#pragma unroll 4
  for (int t = 0; t < lim; ++t) {
    float4 b4 = jb[jbase + t];     // wave-uniform -> broadcast
    float aj = fmaxf(b4.z - b4.x, 0.0f) * fmaxf(b4.w - b4.y, 0.0f);
    int j = j0 + jbase + t;
    bool pred = false;
    if (j > i) {
      float ltx = fmaxf(bi4.x, b4.x), lty = fmaxf(bi4.y, b4.y);
      float rbx = fminf(bi4.z, b4.z), rby = fminf(bi4.w, b4.w);
      float wx = fmaxf(rbx - ltx, 0.0f), wy = fmaxf(rby - lty, 0.0f);
      float inter = wx * wy;
      float den = fmaxf(ai + aj - inter, 1e-9f);
      pred = ((double)inter >= IOU_M * (double)den);  // exact == (inter/den > 0.7f)
    }
    wacc |= ((unsigned long long)(pred ? 1u : 0u)) << t;
  }
  if (iv && jw >= ic && lim > 0) {
    mask[((size_t)bl * PRE + i) * 32 + jw] = wacc;
    if (jw == ic) diagBuf[(size_t)bl * PRE + i] = wacc;
  }
}

// ---------------- Kernel 4: tile NMS — ff1 chain + depth-2 A/B prefetch ----------------
__global__ __launch_bounds__(1024) void k_nms(const unsigned long long* __restrict__ mask,
                                              const unsigned long long* __restrict__ diagBuf,
                                              const float4* __restrict__ sBox,
                                              const float* __restrict__ sScore,
                                              float* __restrict__ catScore,
                                              float4* __restrict__ catBox) {
  __shared__ unsigned long long diag[PRE];
  __shared__ unsigned long long remv[32];
  __shared__ int list[1000];
  __shared__ int sTotal;
  int bl = blockIdx.x, b = bl / 5, l = bl % 5;
  int K = lvlK(l), KP = lvlKP(l), co = l * 1000;
  int tid = threadIdx.x;
  const unsigned long long* mrow = mask + (size_t)bl * PRE * 32;
  int c = tid & 31, g = tid >> 5;
  int nw = (K + 63) >> 6;
  for (int r = tid; r < K; r += 1024) diag[r] = diagBuf[(size_t)bl * PRE + r];
  if (tid < 32) remv[tid] = 0ull;
  __syncthreads();

#define NMS_ISSUE(T, X0, X1)                                         \
  {                                                                  \
    X0 = 0ull; X1 = 0ull;                                            \
    int _t = (T);                                                    \
    if (_t < nw) {                                                   \
      bool _act = (c > _t) && (c < nw);                              \
      int _r0 = _t * 64 + g, _r1 = _r0 + 32;                         \
      if (_act && _r0 < K) X0 = mrow[(size_t)_r0 * 32 + c];          \
      if (_act && _r1 < K) X1 = mrow[(size_t)_r1 * 32 + c];          \
    }                                                                \
  }

#define NMS_CHAIN(T)                                                 \
  if (tid < 64) {                                                    \
    int _t = (T);                                                    \
    int _dr = _t * 64 + tid;                                         \
    unsigned long long _d = (_dr < K) ? diag[_dr] : 0ull;            \
    unsigned long long _local = remv[_t];                            \
    int _lim = min(64, K - _t * 64);                                 \
    unsigned long long _vm = (_lim >= 64) ? ~0ull : ((1ull << _lim) - 1ull); \
    unsigned long long _todo = (~_local) & _vm;                      \
    while (_todo) {                                                  \
      int _i2 = __ffsll((long long)_todo) - 1;                       \
      unsigned _lo = __builtin_amdgcn_readlane((unsigned)_d, _i2);   \
      unsigned _hi = __builtin_amdgcn_readlane((unsigned)(_d >> 32), _i2); \
      unsigned long long _dd = ((unsigned long long)_hi << 32) | (unsigned long long)_lo; \
      _local |= _dd;                                                 \
      _todo &= ~_dd;                                                 \
      _todo &= ~(1ull << _i2);                                       \
    }                                                                \
    if (tid == 0) remv[_t] = _local;                                 \
  }

#define NMS_OR(T, X0, X1)                                            \
  {                                                                  \
    int _t = (T);                                                    \
    unsigned long long _local = remv[_t];                            \
    bool _act = (c > _t) && (c < nw);                                \
    if (_act) {                                                      \
      unsigned long long _acc = 0ull;                                \
      int _r0 = _t * 64 + g, _r1 = _r0 + 32;                         \
      if (_r0 < K && !((_local >> g) & 1ull)) _acc |= X0;            \
      if (_r1 < K && !((_local >> (g + 32)) & 1ull)) _acc |= X1;     \
      if (_acc) atomicOr(&remv[c], _acc);                            \
    }                                                                \
  }

  unsigned long long a0, a1, b0, b1;
  NMS_ISSUE(0, a0, a1)
  NMS_ISSUE(1, b0, b1)
  for (int t = 0; t < nw; t += 2) {
    NMS_CHAIN(t)
    __syncthreads();
    NMS_OR(t, a0, a1)
    NMS_ISSUE(t + 2, a0, a1)
    __syncthreads();
    if (t + 1 < nw) {
      NMS_CHAIN(t + 1)
      __syncthreads();
      NMS_OR(t + 1, b0, b1)
      NMS_ISSUE(t + 3, b0, b1)
      __syncthreads();
    }
  }
#undef NMS_ISSUE
#undef NMS_CHAIN
#undef NMS_OR

  if (tid < 64) {
    int lane = tid;
    bool lv = lane < 32;
    unsigned long long remw = lv ? remv[lane] : 0ull;
    unsigned long long valid = 0ull;
    if (lv) {
      int rem = K - lane * 64;
      valid = (rem >= 64) ? ~0ull : (rem <= 0 ? 0ull : ((1ull << rem) - 1ull));
    }
    unsigned long long keepw = (~remw) & valid;
    unsigned long long suppw = remw & valid;
    unsigned long long lmask = (1ull << lane) - 1ull;
    int base = 0;
    for (int w2 = 0; w2 < 32 && base < KP; ++w2) {
      unsigned long long word = __shfl(keepw, w2);
      int pre = __popcll(word & lmask);
      if (((word >> lane) & 1ull) && (base + pre) < KP) list[base + pre] = w2 * 64 + lane;
      base += __popcll(word);
    }
    int totalKept = base;
    if (totalKept < KP) {
      int b2 = totalKept;
      for (int w2 = 0; w2 < 32 && b2 < KP; ++w2) {
        unsigned long long word = __shfl(suppw, w2);
        int pre = __popcll(word & lmask);
        if (((word >> lane) & 1ull) && (b2 + pre) < KP) list[b2 + pre] = w2 * 64 + lane;
        b2 += __popcll(word);
      }
    }
    if (lane == 0) sTotal = totalKept;
  }
  __syncthreads();
  int totalKept = sTotal;
  for (int t = tid; t < KP; t += 1024) {
    int j = list[t];
    float s = (t < totalKept) ? sScore[bl * PRE + j] : -1.0f;
    catScore[b * CATN + co + t] = s;
    catBox[b * CATN + co + t] = sBox[bl * PRE + j];
  }
}

// ---------------- Kernel 5: final top-1000 via 5-way merge rank ----------------
__global__ __launch_bounds__(256) void k_final(const float* __restrict__ catScore,
                                               const float4* __restrict__ catBox,
                                               float* __restrict__ out) {
  int gid = blockIdx.x * 256 + threadIdx.x;
  if (gid >= NB * CATN) return;
  int b = gid / CATN, p = gid % CATN;
  int c = p / 1000; if (c > 4) c = 4;
  const float* cs = catScore + (size_t)b * CATN;
  float s = cs[p];
  unsigned long long me = ((unsigned long long)keyF(s) << 32) |
                          (unsigned long long)(0xFFFFFFFFu - (unsigned)p);
  int rank = p - c * 1000;
  for (int c2 = 0; c2 < 5; ++c2) {
    if (c2 == c) continue;
    int base = c2 * 1000, len = (c2 == 4) ? 768 : 1000;
    int lo = 0, hi = len;
    while (lo < hi) {
      int mid = (lo + hi) >> 1;
      int q = base + mid;
      unsigned long long k2 = ((unsigned long long)keyF(cs[q]) << 32) |
                              (unsigned long long)(0xFFFFFFFFu - (unsigned)q);
      if (k2 > me) lo = mid + 1; else hi = mid;
    }
    rank += lo;
  }
  if (rank < POST) {
    float4 bx = make_float4(0.0f, 0.0f, 0.0f, 0.0f);
    if (s >= 0.0f) bx = catBox[(size_t)b * CATN + p];
    float* o = out + ((size_t)b * POST + rank) * 5;
    o[0] = (float)b; o[1] = bx.x; o[2] = bx.y; o[3] = bx.z; o[4] = bx.w;
  }
}

extern "C" void kernel_launch(void* const* d_in, const int* in_sizes, int n_in,
                              void* d_out, int out_size, void* d_ws, size_t ws_size,
                              hipStream_t stream) {
  const int prSz[5] = {1572864, 393216, 98304, 24576, 6144};
  const int rgSz[5] = {3145728, 786432, 196608, 49152, 12288};
  const float* pr[5] = {nullptr, nullptr, nullptr, nullptr, nullptr};
  const float* rg[5] = {nullptr, nullptr, nullptr, nullptr, nullptr};
  const float* info = nullptr;
  for (int i = 0; i < n_in; ++i) {
    int s = in_sizes[i];
    bool m = false;
    for (int l = 0; l < 5; ++l) {
      if (s == prSz[l]) { pr[l] = (const float*)d_in[i]; m = true; break; }
      if (s == rgSz[l]) { rg[l] = (const float*)d_in[i]; m = true; break; }
    }
    if (!m && s == 12) info = (const float*)d_in[i];
  }
  InPtrs P;
  P.p0 = pr[0]; P.p1 = pr[1]; P.p2 = pr[2]; P.p3 = pr[3]; P.p4 = pr[4];
  P.r0 = rg[0]; P.r1 = rg[1]; P.r2 = rg[2]; P.r3 = rg[3]; P.r4 = rg[4];
  P.info = info;

  char* w = (char*)d_ws;
  float4* props = (float4*)w;                         w += (size_t)NB * TOTA * 16;
  float4* sBox = (float4*)w;                          w += (size_t)NBL * PRE * 16;
  float4* catBox = (float4*)w;                        w += (size_t)NB * CATN * 16;
  unsigned long long* mask = (unsigned long long*)w;  w += (size_t)NBL * PRE * 32 * 8;
  unsigned long long* cand = (unsigned long long*)w;  w += (size_t)NBL * CANDCAP * 8;
  unsigned long long* diagBuf = (unsigned long long*)w; w += (size_t)NBL * PRE * 8;
  float* scores = (float*)w;                          w += (size_t)NB * TOTA * 4;
  float* sScore = (float*)w;                          w += (size_t)NBL * PRE * 4;
  float* catScore = (float*)w;                        w += (size_t)NB * CATN * 4;
  unsigned* hist8 = (unsigned*)w;                     w += (size_t)NBL * 256 * 4;
  unsigned* hist6 = (unsigned*)w;                     w += (size_t)NBL * 64 * 4;
  unsigned* c1r1 = (unsigned*)w;                      w += (size_t)NBL * 2 * 4;
  unsigned* T14 = (unsigned*)w;                       w += (size_t)NBL * 4;
  unsigned* blockCnt = (unsigned*)w;                  w += (size_t)NBLK * 4;
  unsigned* blockBase = (unsigned*)w;                 w += (size_t)NBLK * 4;
  unsigned* cnt = (unsigned*)w;                       w += (size_t)NBL * 4;
  (void)ws_size; (void)out_size;

  hipMemsetAsync(hist8, 0, (size_t)NBL * (256 + 64) * 4, stream);

  k_decode<<<(NB * TOTA + 255) / 256, 256, 0, stream>>>(P, props, scores);
  k_hist8<<<NB * HBLK, 256, 0, stream>>>(scores, hist8);
  k_thr8<<<NBL, 256, 0, stream>>>(hist8, c1r1);
  k_hist6<<<NB * HBLK, 256, 0, stream>>>(scores, c1r1, hist6);
  k_thr6<<<NBL, 64, 0, stream>>>(hist6, c1r1, T14);
  k_cnt<<<NBLK, 256, 0, stream>>>(scores, T14, blockCnt);
  k_scanblk<<<1, 1024, 0, stream>>>(blockCnt, blockBase, cnt);
  k_fill<<<NBLK, 256, 0, stream>>>(scores, T14, blockBase, cand);
  k_sortc<<<NBL * 8, 256, 0, stream>>>(cand, cnt);
  k_rank<<<NBL * CANDCAP / 256, 256, 0, stream>>>(cand, props, scores, sBox, sScore);
  k_mask<<<NBL * 256, 256, 0, stream>>>(sBox, mask, diagBuf);
  k_nms<<<NBL, 1024, 0, stream>>>(mask, diagBuf, sBox, sScore, catScore, catBox);
  k_final<<<(NB * CATN + 255) / 256, 256, 0, stream>>>(catScore, catBox, (float*)d_out);
}